// Round 2
// baseline (5373.061 us; speedup 1.0000x reference)
//
#include <hip/hip_runtime.h>
#include <hip/hip_fp16.h>
#include <math.h>

#define DEV __device__ __forceinline__

typedef _Float16 f16x2 __attribute__((ext_vector_type(2)));

DEV float wsumf(float v){
  #pragma unroll
  for(int m=32;m>=1;m>>=1) v += __shfl_xor(v,m,64);
  return v;
}
DEV float wmaxf(float v){
  #pragma unroll
  for(int m=32;m>=1;m>>=1) v = fmaxf(v,__shfl_xor(v,m,64));
  return v;
}
DEV unsigned pk2(float a, float b){
  f16x2 h; h.x=(_Float16)a; h.y=(_Float16)b;
  return __builtin_bit_cast(unsigned, h);
}
DEV f16x2 u2h(unsigned u){ return __builtin_bit_cast(f16x2, u); }
DEV float fdot2f(f16x2 a, f16x2 b, float c){
#if __has_builtin(__builtin_amdgcn_fdot2)
  return __builtin_amdgcn_fdot2(a,b,c,false);
#else
  return c + (float)a.x*(float)b.x + (float)a.y*(float)b.y;
#endif
}
DEV float gelu_exact(float g){ return 0.5f*g*(1.f+erff(g*0.70710678118654752f)); }

// ---------------- Part A: codebook attention stack (all fp32) ----------------

// LN(codebook) @ ca_wkv -> kcb, vcb   grid 4096 x 128
__global__ void k_cb_kv(const float* __restrict__ cb, const float* __restrict__ cng,
                        const float* __restrict__ cnb, const float* __restrict__ wkv,
                        float* __restrict__ kcb, float* __restrict__ vcb){
  int r = blockIdx.x;          // b*1024 + j
  int t = threadIdx.x;         // 128 threads
  __shared__ float cn[256]; __shared__ float red[4];
  const float* row = cb + (size_t)r*256;
  float a0 = row[t], a1 = row[t+128];
  float s = wsumf(a0+a1), ss = wsumf(a0*a0+a1*a1);
  int w = t>>6;
  if ((t&63)==0){ red[w] = s; red[2+w] = ss; }
  __syncthreads();
  float mean = (red[0]+red[1])*(1.f/256.f);
  float var  = (red[2]+red[3])*(1.f/256.f) - mean*mean;
  float rstd = rsqrtf(var + 1e-5f);
  cn[t]     = (a0-mean)*rstd*cng[t]+cnb[t];
  cn[t+128] = (a1-mean)*rstd*cng[t+128]+cnb[t+128];
  __syncthreads();
  float acc = 0.f;
  for(int d=0; d<256; d++) acc += cn[d]*wkv[d*128+t];
  if (t<64) kcb[(size_t)r*64 + t] = acc;
  else      vcb[(size_t)r*64 + (t-64)] = acc;
}

// LN(latents) @ ca_wq * 0.125 -> q1 (batch-independent)   grid 512 x 64
__global__ void k_lat_q(const float* __restrict__ latents, const float* __restrict__ ng,
                        const float* __restrict__ nb, const float* __restrict__ wq,
                        float* __restrict__ q1){
  int i = blockIdx.x; int l = threadIdx.x;
  __shared__ float xn[128];
  float a0 = latents[i*128+l], a1 = latents[i*128+64+l];
  float s = wsumf(a0+a1), ss = wsumf(a0*a0+a1*a1);
  float mean = s*(1.f/128.f), var = ss*(1.f/128.f) - mean*mean;
  float rstd = rsqrtf(var+1e-5f);
  xn[l]    = (a0-mean)*rstd*ng[l]+nb[l];
  xn[64+l] = (a1-mean)*rstd*ng[64+l]+nb[64+l];
  __syncthreads();
  float acc=0.f;
  for(int d=0; d<128; d++) acc += xn[d]*wq[d*64+l];
  q1[i*64+l] = acc*0.125f;
}

// cross attention 1 + out proj + residual -> x1   grid (512,4) x 64
__global__ void k_attn1(const float* __restrict__ q1, const float* __restrict__ kcb,
                        const float* __restrict__ vcb, const float* __restrict__ wo,
                        const float* __restrict__ bo, const float* __restrict__ latents,
                        float* __restrict__ x1){
  int b = blockIdx.y, i = blockIdx.x, l = threadIdx.x;
  __shared__ float qs[64], as[1024], os[64];
  qs[l] = q1[i*64+l];
  __syncthreads();
  float s[16];
  const float* kb = kcb + (size_t)b*1024*64;
  for(int t=0;t<16;t++){
    int j = l + 64*t; float acc=0.f;
    const float* kr = kb + (size_t)j*64;
    for(int d=0;d<64;d++) acc += qs[d]*kr[d];
    s[t]=acc;
  }
  float m=-1e30f;
  #pragma unroll
  for(int t=0;t<16;t++) m=fmaxf(m,s[t]);
  m=wmaxf(m);
  float sum=0.f;
  #pragma unroll
  for(int t=0;t<16;t++){ s[t]=__expf(s[t]-m); sum+=s[t]; }
  sum = wsumf(sum); float inv = 1.f/sum;
  #pragma unroll
  for(int t=0;t<16;t++) as[l+64*t] = s[t]*inv;
  __syncthreads();
  const float* vb = vcb + (size_t)b*1024*64;
  float o=0.f;
  for(int j=0;j<1024;j++) o += as[j]*vb[(size_t)j*64+l];
  os[l]=o; __syncthreads();
  float r0 = bo[l]    + latents[i*128+l];
  float r1 = bo[64+l] + latents[i*128+64+l];
  for(int d=0;d<64;d++){ float od=os[d]; r0 += od*wo[d*128+l]; r1 += od*wo[d*128+64+l]; }
  size_t ro = ((size_t)b*512+i)*128;
  x1[ro + l] = r0;
  x1[ro + 64+l] = r1;
}

// generic GEGLU FF on 128-dim rows (hidden 1024 -> 512) + residual   grid 2048 x 256
__global__ void k_ffn(const float* __restrict__ xin, const float* __restrict__ ng,
                      const float* __restrict__ nb, const float* __restrict__ w1,
                      const float* __restrict__ b1, const float* __restrict__ w2,
                      const float* __restrict__ b2, float* __restrict__ xout){
  int r = blockIdx.x; int t = threadIdx.x;
  __shared__ float xi[128], h[128], tf[1024], red[8];
  const float* row = xin + (size_t)r*128;
  float a = (t<128)? row[t] : 0.f;
  float s=wsumf(a), ss=wsumf(a*a);
  int w=t>>6;
  if((t&63)==0){red[w]=s; red[4+w]=ss;}
  __syncthreads();
  float mean=(red[0]+red[1]+red[2]+red[3])*(1.f/128.f);
  float var =(red[4]+red[5]+red[6]+red[7])*(1.f/128.f) - mean*mean;
  float rstd=rsqrtf(var+1e-5f);
  if(t<128){ xi[t]=a; h[t]=(a-mean)*rstd*ng[t]+nb[t]; }
  __syncthreads();
  for(int c=t;c<1024;c+=256){
    float acc=b1[c];
    for(int d=0;d<128;d++) acc+=h[d]*w1[d*1024+c];
    tf[c]=acc;
  }
  __syncthreads();
  for(int c=t;c<512;c+=256){
    tf[c] = tf[c]*gelu_exact(tf[512+c]);
  }
  __syncthreads();
  if(t<128){
    float acc=b2[t];
    for(int d=0;d<512;d++) acc+=tf[d]*w2[d*128+t];
    xout[(size_t)r*128+t] = acc + xi[t];
  }
}

// self-attn qkv projections   grid 2048 x 256
__global__ void k_sa_qkv(const float* __restrict__ xin, const float* __restrict__ ng,
                         const float* __restrict__ nb, const float* __restrict__ wq,
                         const float* __restrict__ wkv, float* __restrict__ saq,
                         float* __restrict__ sak, float* __restrict__ sav){
  int r=blockIdx.x, t=threadIdx.x;
  __shared__ float h[128], red[8];
  const float* row = xin + (size_t)r*128;
  float a = (t<128)? row[t]:0.f;
  float s=wsumf(a), ss=wsumf(a*a);
  int w=t>>6;
  if((t&63)==0){red[w]=s; red[4+w]=ss;}
  __syncthreads();
  float mean=(red[0]+red[1]+red[2]+red[3])*(1.f/128.f);
  float var =(red[4]+red[5]+red[6]+red[7])*(1.f/128.f)-mean*mean;
  float rstd=rsqrtf(var+1e-5f);
  if(t<128) h[t]=(a-mean)*rstd*ng[t]+nb[t];
  __syncthreads();
  for(int c=t;c<512;c+=256){
    float aq=0.f, ak=0.f, av=0.f;
    for(int d=0;d<128;d++){
      float hd=h[d];
      aq += hd*wq[d*512+c];
      ak += hd*wkv[d*1024+c];
      av += hd*wkv[d*1024+512+c];
    }
    size_t o=(size_t)r*512+c;
    saq[o]=aq*0.125f; sak[o]=ak; sav[o]=av;
  }
}

// self-attn core   grid (128,8,4) x 256 (4 waves = 4 query rows)
__global__ void k_sa_attn(const float* __restrict__ saq, const float* __restrict__ sak,
                          const float* __restrict__ sav, float* __restrict__ sao){
  int b=blockIdx.z, hh=blockIdx.y;
  int w=threadIdx.x>>6, l=threadIdx.x&63;
  int i=blockIdx.x*4+w;
  __shared__ float qs[4][64]; __shared__ float as[4][512];
  qs[w][l]=saq[((size_t)b*512+i)*512+hh*64+l];
  __syncthreads();
  const float* kb = sak + (size_t)b*512*512 + hh*64;
  float s[8];
  #pragma unroll
  for(int t=0;t<8;t++){
    int j=l+64*t; const float* kr=kb+(size_t)j*512; float acc=0.f;
    for(int d=0;d<64;d++) acc+=qs[w][d]*kr[d];
    s[t]=acc;
  }
  float m=-1e30f;
  #pragma unroll
  for(int t=0;t<8;t++) m=fmaxf(m,s[t]);
  m=wmaxf(m);
  float sum=0.f;
  #pragma unroll
  for(int t=0;t<8;t++){ s[t]=__expf(s[t]-m); sum+=s[t]; }
  sum=wsumf(sum);
  float inv=1.f/sum;
  #pragma unroll
  for(int t=0;t<8;t++) as[w][l+64*t]=s[t]*inv;
  __syncthreads();
  const float* vb = sav + (size_t)b*512*512 + hh*64;
  float o=0.f;
  for(int j=0;j<512;j++) o += as[w][j]*vb[(size_t)j*512+l];
  sao[((size_t)b*512+i)*512+hh*64+l]=o;
}

// self-attn out proj + residual   grid 2048 x 256
__global__ void k_sa_proj(const float* __restrict__ sao, const float* __restrict__ wo,
                          const float* __restrict__ bo, const float* __restrict__ resid,
                          float* __restrict__ xout){
  int r=blockIdx.x, t=threadIdx.x;
  __shared__ float o[512]; __shared__ float acc2[256];
  o[t]=sao[(size_t)r*512+t]; o[256+t]=sao[(size_t)r*512+256+t];
  __syncthreads();
  int c = t&127; int half = t>>7;
  float acc=0.f;
  int d0 = half*256;
  for(int d=d0; d<d0+256; d++) acc += o[d]*wo[d*128+c];
  acc2[t]=acc; __syncthreads();
  if(t<128) xout[(size_t)r*128+t] = acc2[t]+acc2[t+128]+bo[t]+resid[(size_t)r*128+t];
}

// LN(lat) @ qa_wkv -> packed f16 kp, vp   grid 2048 x 128
__global__ void k_kv2p(const float* __restrict__ lat, const float* __restrict__ cng,
                       const float* __restrict__ cnb, const float* __restrict__ wkv,
                       unsigned* __restrict__ kp, unsigned* __restrict__ vp){
  int r=blockIdx.x, t=threadIdx.x;
  __shared__ float cn[128]; __shared__ float red[4]; __shared__ float kv[128];
  float a = lat[(size_t)r*128+t];
  float s=wsumf(a), ss=wsumf(a*a);
  int w=t>>6;
  if((t&63)==0){red[w]=s;red[2+w]=ss;}
  __syncthreads();
  float mean=(red[0]+red[1])*(1.f/128.f), var=(red[2]+red[3])*(1.f/128.f)-mean*mean;
  float rstd=rsqrtf(var+1e-5f);
  cn[t]=(a-mean)*rstd*cng[t]+cnb[t];
  __syncthreads();
  float acc=0.f;
  for(int d=0;d<128;d++) acc+=cn[d]*wkv[d*128+t];
  kv[t]=acc;
  __syncthreads();
  if(t<32)               kp[(size_t)r*32 + t]      = pk2(kv[2*t],      kv[2*t+1]);
  else if(t>=64 && t<96) vp[(size_t)r*32 + (t-64)] = pk2(kv[64+2*(t-64)], kv[64+2*(t-64)+1]);
}

// ---------------- Part B1: the big coordinate attention ----------------
// grid 2048 x 512, dynamic LDS 131072 B (K swizzled + V linear, f16).
// One wave per point; wq/wo columns live in per-lane registers.
__global__ void __launch_bounds__(512,1) k_coord_attn(
    const float* __restrict__ queries, const unsigned* __restrict__ kp_g,
    const unsigned* __restrict__ vp_g, const float* __restrict__ qng,
    const float* __restrict__ qnb, const float* __restrict__ wq,
    const float* __restrict__ wo, const float* __restrict__ bo,
    float* __restrict__ out){
  extern __shared__ unsigned lds[];
  unsigned* kls=lds;                 // 16384 u32, [j][quad^(j&7)][4] swizzled
  unsigned* vls=lds+16384;           // 16384 u32, linear [j][d2]
  int tid=threadIdx.x, l=tid&63, w=tid>>6;
  int b=blockIdx.x>>9, grp=blockIdx.x&511;
  const unsigned* kg=kp_g+(size_t)b*16384;
  const unsigned* vg=vp_g+(size_t)b*16384;
  for(int idx=tid; idx<16384; idx+=512){
    int e2=idx&31, j=idx>>5;
    kls[(j<<5)+((((e2>>2)^(j&7))<<2)|(e2&3))]=kg[idx];
    vls[idx]=vg[idx];
  }
  // wq/wo columns for this lane -> registers (compile-time indexed)
  unsigned wqreg[32], woreg[32];
  #pragma unroll
  for(int e2=0;e2<32;e2++){
    wqreg[e2]=pk2(wq[(2*e2)*64+l], wq[(2*e2+1)*64+l]);
    woreg[e2]=pk2(wo[(2*e2)*64+l], wo[(2*e2+1)*64+l]);
  }
  float bol = bo[l];
  float gLn=qng[l], bLn=qnb[l];
  __syncthreads();
  int l7=l&7, h8=l>>3, lp=l&31;
  for(int p=0;p<16;p++){
    int i=grp*128+w*16+p;
    const float* yr=queries+((size_t)b*65536+i)*64;
    float y=yr[l];
    float mean=wsumf(y)*(1.f/64.f);
    float ex2=wsumf(y*y)*(1.f/64.f);
    float rstd=rsqrtf(ex2-mean*mean+1e-5f);
    float yn=(y-mean)*rstd*gLn+bLn;
    unsigned ynp=pk2(__shfl(yn,2*lp,64), __shfl(yn,2*lp+1,64));
    float q=0.f;
    #pragma unroll
    for(int e2=0;e2<32;e2++){
      unsigned yb=(unsigned)__shfl((int)ynp,e2,64);
      q=fdot2f(u2h(wqreg[e2]), u2h(yb), q);
    }
    q*=0.125f;
    unsigned qp=pk2(__shfl(q,2*lp,64), __shfl(q,2*lp+1,64));
    float s[8];
    #pragma unroll
    for(int t=0;t<8;t++) s[t]=0.f;
    #pragma unroll
    for(int si=0;si<8;si++){
      f16x2 qa=u2h((unsigned)__shfl((int)qp,4*si+0,64));
      f16x2 qb=u2h((unsigned)__shfl((int)qp,4*si+1,64));
      f16x2 qc=u2h((unsigned)__shfl((int)qp,4*si+2,64));
      f16x2 qd=u2h((unsigned)__shfl((int)qp,4*si+3,64));
      #pragma unroll
      for(int t=0;t<8;t++){
        const uint4 kk=*(const uint4*)&kls[((l+64*t)<<5)+((si^l7)<<2)];
        s[t]=fdot2f(u2h(kk.x),qa,s[t]);
        s[t]=fdot2f(u2h(kk.y),qb,s[t]);
        s[t]=fdot2f(u2h(kk.z),qc,s[t]);
        s[t]=fdot2f(u2h(kk.w),qd,s[t]);
      }
    }
    float m=-1e30f;
    #pragma unroll
    for(int t=0;t<8;t++) m=fmaxf(m,s[t]);
    m=wmaxf(m);
    float sum=0.f;
    #pragma unroll
    for(int t=0;t<8;t++){ s[t]=__expf(s[t]-m); sum+=s[t]; }
    sum=wsumf(sum);
    float inv=1.f/sum;
    #pragma unroll
    for(int t=0;t<8;t++) s[t]*=inv;
    f16x2 o0=u2h(0u), o1=u2h(0u), o2=u2h(0u), o3=u2h(0u);
    #pragma unroll
    for(int gi=0;gi<64;gi++){
      int j=gi*8+h8;
      const uint4 vv=*(const uint4*)&vls[(j<<5)+(l7<<2)];
      float av=__shfl(s[gi>>3], 8*(gi&7)+h8, 64);
      f16x2 ah; ah.x=(_Float16)av; ah.y=ah.x;
      o0 += u2h(vv.x)*ah;
      o1 += u2h(vv.y)*ah;
      o2 += u2h(vv.z)*ah;
      o3 += u2h(vv.w)*ah;
    }
    #pragma unroll
    for(int msk=8;msk<=32;msk<<=1){
      o0 += u2h((unsigned)__shfl_xor(__builtin_bit_cast(int,o0),msk,64));
      o1 += u2h((unsigned)__shfl_xor(__builtin_bit_cast(int,o1),msk,64));
      o2 += u2h((unsigned)__shfl_xor(__builtin_bit_cast(int,o2),msk,64));
      o3 += u2h((unsigned)__shfl_xor(__builtin_bit_cast(int,o3),msk,64));
    }
    float r=bol;
    #pragma unroll
    for(int d2=0;d2<32;d2++){
      unsigned osel = (d2&3)==0?__builtin_bit_cast(unsigned,o0):
                      (d2&3)==1?__builtin_bit_cast(unsigned,o1):
                      (d2&3)==2?__builtin_bit_cast(unsigned,o2):
                                __builtin_bit_cast(unsigned,o3);
      f16x2 op=u2h((unsigned)__shfl((int)osel, d2>>2, 64));
      r=fdot2f(op, u2h(woreg[d2]), r);
    }
    out[((size_t)b*65536+i)*64+l]=r+y;
  }
}

// ---------------- Part B2: decoder FF, in place on d_out ----------------
// grid 2048 x 256, each wave 32 rows
__global__ void __launch_bounds__(256) k_ffq(
    float* __restrict__ y, const float* __restrict__ ng, const float* __restrict__ nb,
    const float* __restrict__ w1, const float* __restrict__ b1,
    const float* __restrict__ w2, const float* __restrict__ b2){
  __shared__ unsigned w1p[4096];
  __shared__ unsigned w2p[2048];
  __shared__ float b1L[128], b2L[64], gL[64], nbL[64];
  int tid=threadIdx.x, l=tid&63, w=tid>>6;
  for(int idx=tid;idx<4096;idx+=256){
    int e2=idx>>7, c=idx&127;
    w1p[idx]=pk2(w1[(2*e2)*128+c], w1[(2*e2+1)*128+c]);
  }
  for(int idx=tid;idx<2048;idx+=256){
    int d2=idx>>6, c=idx&63;
    w2p[idx]=pk2(w2[(2*d2)*64+c], w2[(2*d2+1)*64+c]);
  }
  if(tid<128) b1L[tid]=b1[tid];
  if(tid<64){b2L[tid]=b2[tid]; gL[tid]=ng[tid]; nbL[tid]=nb[tid];}
  __syncthreads();
  float gq=gL[l], gb=nbL[l], ba=b1L[l], bgg=b1L[64+l], b2v=b2L[l];
  int lp=l&31;
  size_t r0=(size_t)blockIdx.x*128 + (size_t)w*32;
  for(int p=0;p<32;p++){
    size_t r=r0+p;
    float yv=y[r*64+l];
    float mean=wsumf(yv)*(1.f/64.f);
    float ex2=wsumf(yv*yv)*(1.f/64.f);
    float rstd=rsqrtf(ex2-mean*mean+1e-5f);
    float hn=(yv-mean)*rstd*gq+gb;
    unsigned hp=pk2(__shfl(hn,2*lp,64),__shfl(hn,2*lp+1,64));
    float ta=ba, tg=bgg;
    #pragma unroll
    for(int e2=0;e2<32;e2++){
      f16x2 hb=u2h((unsigned)__shfl((int)hp,e2,64));
      ta=fdot2f(u2h(w1p[e2*128+l]),hb,ta);
      tg=fdot2f(u2h(w1p[e2*128+64+l]),hb,tg);
    }
    float u=ta*gelu_exact(tg);
    unsigned up=pk2(__shfl(u,2*lp,64),__shfl(u,2*lp+1,64));
    float acc=b2v;
    #pragma unroll
    for(int d2=0;d2<32;d2++){
      acc=fdot2f(u2h(w2p[d2*64+l]),u2h((unsigned)__shfl((int)up,d2,64)),acc);
    }
    y[r*64+l]=acc+yv;
  }
}

extern "C" void kernel_launch(void* const* d_in, const int* in_sizes, int n_in,
                              void* d_out, int out_size, void* d_ws, size_t ws_size,
                              hipStream_t stream){
  const float* cb      =(const float*)d_in[0];
  const float* queries =(const float*)d_in[1];
  const float* latents =(const float*)d_in[2];
  const float* ca_ng=(const float*)d_in[3],  *ca_nb=(const float*)d_in[4];
  const float* ca_cng=(const float*)d_in[5], *ca_cnb=(const float*)d_in[6];
  const float* ca_wq=(const float*)d_in[7],  *ca_wkv=(const float*)d_in[8];
  const float* ca_wo=(const float*)d_in[9],  *ca_bo=(const float*)d_in[10];
  const float* cf_ng=(const float*)d_in[11], *cf_nb=(const float*)d_in[12];
  const float* cf_w1=(const float*)d_in[13], *cf_b1=(const float*)d_in[14];
  const float* cf_w2=(const float*)d_in[15], *cf_b2=(const float*)d_in[16];
  const float* sa_ng=(const float*)d_in[17], *sa_nb=(const float*)d_in[18];
  const float* sa_wq=(const float*)d_in[19], *sa_wkv=(const float*)d_in[20];
  const float* sa_wo=(const float*)d_in[21], *sa_bo=(const float*)d_in[22];
  const float* sf_ng=(const float*)d_in[23], *sf_nb=(const float*)d_in[24];
  const float* sf_w1=(const float*)d_in[25], *sf_b1=(const float*)d_in[26];
  const float* sf_w2=(const float*)d_in[27], *sf_b2=(const float*)d_in[28];
  const float* qa_ng=(const float*)d_in[29], *qa_nb=(const float*)d_in[30];
  const float* qa_cng=(const float*)d_in[31],*qa_cnb=(const float*)d_in[32];
  const float* qa_wq=(const float*)d_in[33], *qa_wkv=(const float*)d_in[34];
  const float* qa_wo=(const float*)d_in[35], *qa_bo=(const float*)d_in[36];
  const float* qf_ng=(const float*)d_in[37], *qf_nb=(const float*)d_in[38];
  const float* qf_w1=(const float*)d_in[39], *qf_b1=(const float*)d_in[40];
  const float* qf_w2=(const float*)d_in[41], *qf_b2=(const float*)d_in[42];
  float* out=(float*)d_out;

  // Part-A scratch lives inside d_out (64 MB; all of it is overwritten by
  // k_coord_attn + k_ffq before validation). Peak usage 5,799,936 floats.
  float* kcb = out;                 // 262144
  float* vcb = kcb + 262144;        // 262144
  float* q1  = vcb + 262144;        // 32768
  float* x1  = q1  + 32768;         // 262144
  float* x2  = x1  + 262144;        // 262144
  float* x3  = x2  + 262144;        // 262144
  float* lat = x3  + 262144;        // 262144
  float* saq = lat + 262144;        // 1048576
  float* sak = saq + 1048576;       // 1048576
  float* sav = sak + 1048576;       // 1048576
  float* sao = sav + 1048576;       // 1048576 -> total 5,799,936 < 16,777,216

  // Only kp/vp must survive into k_coord_attn (which overwrites d_out):
  // they live in d_ws. Total ws usage: 512 KB.
  unsigned* kp=(unsigned*)d_ws;     // 65536 u32
  unsigned* vp=kp+65536;            // 65536 u32

  k_cb_kv<<<4096,128,0,stream>>>(cb,ca_cng,ca_cnb,ca_wkv,kcb,vcb);
  k_lat_q<<<512,64,0,stream>>>(latents,ca_ng,ca_nb,ca_wq,q1);
  k_attn1<<<dim3(512,4),64,0,stream>>>(q1,kcb,vcb,ca_wo,ca_bo,latents,x1);
  k_ffn<<<2048,256,0,stream>>>(x1,cf_ng,cf_nb,cf_w1,cf_b1,cf_w2,cf_b2,x2);
  k_sa_qkv<<<2048,256,0,stream>>>(x2,sa_ng,sa_nb,sa_wq,sa_wkv,saq,sak,sav);
  k_sa_attn<<<dim3(128,8,4),256,0,stream>>>(saq,sak,sav,sao);
  k_sa_proj<<<2048,256,0,stream>>>(sao,sa_wo,sa_bo,x2,x3);
  k_ffn<<<2048,256,0,stream>>>(x3,sf_ng,sf_nb,sf_w1,sf_b1,sf_w2,sf_b2,lat);
  k_kv2p<<<2048,128,0,stream>>>(lat,qa_cng,qa_cnb,qa_wkv,kp,vp);
  hipFuncSetAttribute((const void*)k_coord_attn,
                      hipFuncAttributeMaxDynamicSharedMemorySize, 131072);
  k_coord_attn<<<2048,512,131072,stream>>>(queries,kp,vp,qa_ng,qa_nb,qa_wq,qa_wo,qa_bo,out);
  k_ffq<<<2048,256,0,stream>>>(out,qf_ng,qf_nb,qf_w1,qf_b1,qf_w2,qf_b2);
}

// Round 3
// 1810.872 us; speedup vs baseline: 2.9671x; 2.9671x over previous
//
#include <hip/hip_runtime.h>
#include <hip/hip_fp16.h>
#include <math.h>

#define DEV __device__ __forceinline__

typedef _Float16 f16x2 __attribute__((ext_vector_type(2)));

DEV float wsumf(float v){
  #pragma unroll
  for(int m=32;m>=1;m>>=1) v += __shfl_xor(v,m,64);
  return v;
}
DEV float wmaxf(float v){
  #pragma unroll
  for(int m=32;m>=1;m>>=1) v = fmaxf(v,__shfl_xor(v,m,64));
  return v;
}
DEV unsigned pk2(float a, float b){
  f16x2 h; h.x=(_Float16)a; h.y=(_Float16)b;
  return __builtin_bit_cast(unsigned, h);
}
DEV f16x2 u2h(unsigned u){ return __builtin_bit_cast(f16x2, u); }
DEV float fdot2f(f16x2 a, f16x2 b, float c){
#if __has_builtin(__builtin_amdgcn_fdot2)
  return __builtin_amdgcn_fdot2(a,b,c,false);
#else
  return c + (float)a.x*(float)b.x + (float)a.y*(float)b.y;
#endif
}
DEV float gelu_exact(float g){ return 0.5f*g*(1.f+erff(g*0.70710678118654752f)); }

// ---------------- Part A: codebook attention stack (all fp32) ----------------

__global__ void k_cb_kv(const float* __restrict__ cb, const float* __restrict__ cng,
                        const float* __restrict__ cnb, const float* __restrict__ wkv,
                        float* __restrict__ kcb, float* __restrict__ vcb){
  int r = blockIdx.x;          // b*1024 + j
  int t = threadIdx.x;         // 128 threads
  __shared__ float cn[256]; __shared__ float red[4];
  const float* row = cb + (size_t)r*256;
  float a0 = row[t], a1 = row[t+128];
  float s = wsumf(a0+a1), ss = wsumf(a0*a0+a1*a1);
  int w = t>>6;
  if ((t&63)==0){ red[w] = s; red[2+w] = ss; }
  __syncthreads();
  float mean = (red[0]+red[1])*(1.f/256.f);
  float var  = (red[2]+red[3])*(1.f/256.f) - mean*mean;
  float rstd = rsqrtf(var + 1e-5f);
  cn[t]     = (a0-mean)*rstd*cng[t]+cnb[t];
  cn[t+128] = (a1-mean)*rstd*cng[t+128]+cnb[t+128];
  __syncthreads();
  float acc = 0.f;
  for(int d=0; d<256; d++) acc += cn[d]*wkv[d*128+t];
  if (t<64) kcb[(size_t)r*64 + t] = acc;
  else      vcb[(size_t)r*64 + (t-64)] = acc;
}

__global__ void k_lat_q(const float* __restrict__ latents, const float* __restrict__ ng,
                        const float* __restrict__ nb, const float* __restrict__ wq,
                        float* __restrict__ q1){
  int i = blockIdx.x; int l = threadIdx.x;
  __shared__ float xn[128];
  float a0 = latents[i*128+l], a1 = latents[i*128+64+l];
  float s = wsumf(a0+a1), ss = wsumf(a0*a0+a1*a1);
  float mean = s*(1.f/128.f), var = ss*(1.f/128.f) - mean*mean;
  float rstd = rsqrtf(var+1e-5f);
  xn[l]    = (a0-mean)*rstd*ng[l]+nb[l];
  xn[64+l] = (a1-mean)*rstd*ng[64+l]+nb[64+l];
  __syncthreads();
  float acc=0.f;
  for(int d=0; d<128; d++) acc += xn[d]*wq[d*64+l];
  q1[i*64+l] = acc*0.125f;
}

__global__ void k_attn1(const float* __restrict__ q1, const float* __restrict__ kcb,
                        const float* __restrict__ vcb, const float* __restrict__ wo,
                        const float* __restrict__ bo, const float* __restrict__ latents,
                        float* __restrict__ x1){
  int b = blockIdx.y, i = blockIdx.x, l = threadIdx.x;
  __shared__ float qs[64], as[1024], os[64];
  qs[l] = q1[i*64+l];
  __syncthreads();
  float s[16];
  const float* kb = kcb + (size_t)b*1024*64;
  for(int t=0;t<16;t++){
    int j = l + 64*t; float acc=0.f;
    const float* kr = kb + (size_t)j*64;
    for(int d=0;d<64;d++) acc += qs[d]*kr[d];
    s[t]=acc;
  }
  float m=-1e30f;
  #pragma unroll
  for(int t=0;t<16;t++) m=fmaxf(m,s[t]);
  m=wmaxf(m);
  float sum=0.f;
  #pragma unroll
  for(int t=0;t<16;t++){ s[t]=__expf(s[t]-m); sum+=s[t]; }
  sum = wsumf(sum); float inv = 1.f/sum;
  #pragma unroll
  for(int t=0;t<16;t++) as[l+64*t] = s[t]*inv;
  __syncthreads();
  const float* vb = vcb + (size_t)b*1024*64;
  float o=0.f;
  for(int j=0;j<1024;j++) o += as[j]*vb[(size_t)j*64+l];
  os[l]=o; __syncthreads();
  float r0 = bo[l]    + latents[i*128+l];
  float r1 = bo[64+l] + latents[i*128+64+l];
  for(int d=0;d<64;d++){ float od=os[d]; r0 += od*wo[d*128+l]; r1 += od*wo[d*128+64+l]; }
  size_t ro = ((size_t)b*512+i)*128;
  x1[ro + l] = r0;
  x1[ro + 64+l] = r1;
}

__global__ void k_ffn(const float* __restrict__ xin, const float* __restrict__ ng,
                      const float* __restrict__ nb, const float* __restrict__ w1,
                      const float* __restrict__ b1, const float* __restrict__ w2,
                      const float* __restrict__ b2, float* __restrict__ xout){
  int r = blockIdx.x; int t = threadIdx.x;
  __shared__ float xi[128], h[128], tf[1024], red[8];
  const float* row = xin + (size_t)r*128;
  float a = (t<128)? row[t] : 0.f;
  float s=wsumf(a), ss=wsumf(a*a);
  int w=t>>6;
  if((t&63)==0){red[w]=s; red[4+w]=ss;}
  __syncthreads();
  float mean=(red[0]+red[1]+red[2]+red[3])*(1.f/128.f);
  float var =(red[4]+red[5]+red[6]+red[7])*(1.f/128.f) - mean*mean;
  float rstd=rsqrtf(var+1e-5f);
  if(t<128){ xi[t]=a; h[t]=(a-mean)*rstd*ng[t]+nb[t]; }
  __syncthreads();
  for(int c=t;c<1024;c+=256){
    float acc=b1[c];
    for(int d=0;d<128;d++) acc+=h[d]*w1[d*1024+c];
    tf[c]=acc;
  }
  __syncthreads();
  for(int c=t;c<512;c+=256){
    tf[c] = tf[c]*gelu_exact(tf[512+c]);
  }
  __syncthreads();
  if(t<128){
    float acc=b2[t];
    for(int d=0;d<512;d++) acc+=tf[d]*w2[d*128+t];
    xout[(size_t)r*128+t] = acc + xi[t];
  }
}

__global__ void k_sa_qkv(const float* __restrict__ xin, const float* __restrict__ ng,
                         const float* __restrict__ nb, const float* __restrict__ wq,
                         const float* __restrict__ wkv, float* __restrict__ saq,
                         float* __restrict__ sak, float* __restrict__ sav){
  int r=blockIdx.x, t=threadIdx.x;
  __shared__ float h[128], red[8];
  const float* row = xin + (size_t)r*128;
  float a = (t<128)? row[t]:0.f;
  float s=wsumf(a), ss=wsumf(a*a);
  int w=t>>6;
  if((t&63)==0){red[w]=s; red[4+w]=ss;}
  __syncthreads();
  float mean=(red[0]+red[1]+red[2]+red[3])*(1.f/128.f);
  float var =(red[4]+red[5]+red[6]+red[7])*(1.f/128.f)-mean*mean;
  float rstd=rsqrtf(var+1e-5f);
  if(t<128) h[t]=(a-mean)*rstd*ng[t]+nb[t];
  __syncthreads();
  for(int c=t;c<512;c+=256){
    float aq=0.f, ak=0.f, av=0.f;
    for(int d=0;d<128;d++){
      float hd=h[d];
      aq += hd*wq[d*512+c];
      ak += hd*wkv[d*1024+c];
      av += hd*wkv[d*1024+512+c];
    }
    size_t o=(size_t)r*512+c;
    saq[o]=aq*0.125f; sak[o]=ak; sav[o]=av;
  }
}

__global__ void k_sa_attn(const float* __restrict__ saq, const float* __restrict__ sak,
                          const float* __restrict__ sav, float* __restrict__ sao){
  int b=blockIdx.z, hh=blockIdx.y;
  int w=threadIdx.x>>6, l=threadIdx.x&63;
  int i=blockIdx.x*4+w;
  __shared__ float qs[4][64]; __shared__ float as[4][512];
  qs[w][l]=saq[((size_t)b*512+i)*512+hh*64+l];
  __syncthreads();
  const float* kb = sak + (size_t)b*512*512 + hh*64;
  float s[8];
  #pragma unroll
  for(int t=0;t<8;t++){
    int j=l+64*t; const float* kr=kb+(size_t)j*512; float acc=0.f;
    for(int d=0;d<64;d++) acc+=qs[w][d]*kr[d];
    s[t]=acc;
  }
  float m=-1e30f;
  #pragma unroll
  for(int t=0;t<8;t++) m=fmaxf(m,s[t]);
  m=wmaxf(m);
  float sum=0.f;
  #pragma unroll
  for(int t=0;t<8;t++){ s[t]=__expf(s[t]-m); sum+=s[t]; }
  sum=wsumf(sum);
  float inv=1.f/sum;
  #pragma unroll
  for(int t=0;t<8;t++) as[w][l+64*t]=s[t]*inv;
  __syncthreads();
  const float* vb = sav + (size_t)b*512*512 + hh*64;
  float o=0.f;
  for(int j=0;j<512;j++) o += as[w][j]*vb[(size_t)j*512+l];
  sao[((size_t)b*512+i)*512+hh*64+l]=o;
}

__global__ void k_sa_proj(const float* __restrict__ sao, const float* __restrict__ wo,
                          const float* __restrict__ bo, const float* __restrict__ resid,
                          float* __restrict__ xout){
  int r=blockIdx.x, t=threadIdx.x;
  __shared__ float o[512]; __shared__ float acc2[256];
  o[t]=sao[(size_t)r*512+t]; o[256+t]=sao[(size_t)r*512+256+t];
  __syncthreads();
  int c = t&127; int half = t>>7;
  float acc=0.f;
  int d0 = half*256;
  for(int d=d0; d<d0+256; d++) acc += o[d]*wo[d*128+c];
  acc2[t]=acc; __syncthreads();
  if(t<128) xout[(size_t)r*128+t] = acc2[t]+acc2[t+128]+bo[t]+resid[(size_t)r*128+t];
}

// LN(lat) @ qa_wkv -> packed f16 kp, vp   grid 2048 x 128
__global__ void k_kv2p(const float* __restrict__ lat, const float* __restrict__ cng,
                       const float* __restrict__ cnb, const float* __restrict__ wkv,
                       unsigned* __restrict__ kp, unsigned* __restrict__ vp){
  int r=blockIdx.x, t=threadIdx.x;
  __shared__ float cn[128]; __shared__ float red[4]; __shared__ float kv[128];
  float a = lat[(size_t)r*128+t];
  float s=wsumf(a), ss=wsumf(a*a);
  int w=t>>6;
  if((t&63)==0){red[w]=s;red[2+w]=ss;}
  __syncthreads();
  float mean=(red[0]+red[1])*(1.f/128.f), var=(red[2]+red[3])*(1.f/128.f)-mean*mean;
  float rstd=rsqrtf(var+1e-5f);
  cn[t]=(a-mean)*rstd*cng[t]+cnb[t];
  __syncthreads();
  float acc=0.f;
  for(int d=0;d<128;d++) acc+=cn[d]*wkv[d*128+t];
  kv[t]=acc;
  __syncthreads();
  if(t<32)               kp[(size_t)r*32 + t]      = pk2(kv[2*t],      kv[2*t+1]);
  else if(t>=64 && t<96) vp[(size_t)r*32 + (t-64)] = pk2(kv[64+2*(t-64)], kv[64+2*(t-64)+1]);
}

// ---------------- Part B1: coordinate attention, point-per-lane ----------------
// grid 512 x 512, dynamic LDS 152576 B. Lane owns one query row; all K/V/weight
// LDS reads are wave-uniform broadcasts; LN folded into projection constants.
// LDS map (u32 offsets):
#define KLS 0        // [j=512][d2=32] f16x2 K pairs (over d)
#define VLS 16384    // [j=512][d2=32] f16x2 V pairs (over d)
#define GWQ 32768    // [e2=32][d=64]  f16x2 (g_e * wq[e][d]) pairs over e
#define WOP 34816    // [d2=33][r=64]  f16x2 wo pairs over d; row 32 = (bo_r, 0)
#define CSKo 36928   // [512] f32: 0.125 * (cs . K_j)
#define CNKo 37440   // [512] f32: 0.125 * (cn . K_j)
#define CSF 37952    // [64] f32 tmp
#define CNF 38016    // [64] f32 tmp
#define CS2 38080    // [32] f16x2 packed cs
#define CN2 38112    // [32] f16x2 packed cn
#define LDSU32 38144

__global__ void __launch_bounds__(512,1) k_coord_pt(
    const float* __restrict__ queries, const unsigned* __restrict__ kp_g,
    const unsigned* __restrict__ vp_g, const float* __restrict__ ng,
    const float* __restrict__ nb, const float* __restrict__ wq,
    const float* __restrict__ wo, const float* __restrict__ bo,
    float* __restrict__ out){
  extern __shared__ unsigned lds[];
  int tid=threadIdx.x;
  int b = blockIdx.x>>7;                       // 128 blocks per batch
  const unsigned* kg=kp_g+(size_t)b*16384;
  const unsigned* vg=vp_g+(size_t)b*16384;
  // ---- stage K/V (coalesced uint4 copies) ----
  for(int idx=tid; idx<4096; idx+=512){
    ((uint4*)(lds+KLS))[idx]=((const uint4*)kg)[idx];
    ((uint4*)(lds+VLS))[idx]=((const uint4*)vg)[idx];
  }
  // ---- stage g-folded wq, wo(+bo row) ----
  for(int idx=tid; idx<2048; idx+=512){
    int e2=idx>>6, d=idx&63;
    lds[GWQ+idx]=pk2(ng[2*e2]*wq[(2*e2)*64+d], ng[2*e2+1]*wq[(2*e2+1)*64+d]);
  }
  for(int idx=tid; idx<2112; idx+=512){
    int d2=idx>>6, r=idx&63;
    lds[WOP+idx]=(d2<32)? pk2(wo[(2*d2)*64+r], wo[(2*d2+1)*64+r]) : pk2(bo[r],0.f);
  }
  // ---- LN-fold column sums: cs_d = sum_e g_e wq[e][d]; cn_d = sum_e b_e wq[e][d]
  if(tid<64){
    float cs=0.f, cn=0.f;
    for(int e=0;e<64;e++){ float wv=wq[e*64+tid]; cs+=ng[e]*wv; cn+=nb[e]*wv; }
    ((float*)(lds+CSF))[tid]=cs; ((float*)(lds+CNF))[tid]=cn;
  }
  __syncthreads();
  if(tid<32){
    const float* csf=(const float*)(lds+CSF); const float* cnf=(const float*)(lds+CNF);
    lds[CS2+tid]=pk2(csf[2*tid],csf[2*tid+1]);
    lds[CN2+tid]=pk2(cnf[2*tid],cnf[2*tid+1]);
  }
  __syncthreads();
  { // per-j constants: csk_j = 0.125*(cs.K_j), cnk_j = 0.125*(cn.K_j); tid = j
    float a=0.f, c=0.f;
    #pragma unroll 1
    for(int d2=0; d2<32; d2++){
      f16x2 kk=u2h(lds[KLS + tid*32 + d2]);
      a=fdot2f(u2h(lds[CS2+d2]),kk,a);
      c=fdot2f(u2h(lds[CN2+d2]),kk,c);
    }
    ((float*)(lds+CSKo))[tid]=0.125f*a;
    ((float*)(lds+CNKo))[tid]=0.125f*c;
  }
  __syncthreads();

  // ---- main: one point per lane ----
  size_t row=(size_t)blockIdx.x*512 + tid;
  const float* yr=queries+row*64;
  // load y + LN stats (lane-local, no shuffles)
  float ysum=0.f, ysq=0.f;
  unsigned yp2[32];
  {
    float4 yv[16];
    #pragma unroll
    for(int i=0;i<16;i++){
      yv[i]=((const float4*)yr)[i];
      ysum += (yv[i].x+yv[i].y)+(yv[i].z+yv[i].w);
      ysq  += yv[i].x*yv[i].x+yv[i].y*yv[i].y+yv[i].z*yv[i].z+yv[i].w*yv[i].w;
    }
    #pragma unroll
    for(int i=0;i<16;i++){
      yp2[2*i]  =pk2(yv[i].x,yv[i].y);
      yp2[2*i+1]=pk2(yv[i].z,yv[i].w);
    }
  }
  float mean=ysum*(1.f/64.f);
  float rstd=rsqrtf(ysq*(1.f/64.f)-mean*mean+1e-5f);
  float rm=rstd*mean;
  // q-projection: rawq_d = sum_e y_e * g_e * wq[e][d]
  float rawq[64];
  #pragma unroll
  for(int d=0;d<64;d++) rawq[d]=0.f;
  #pragma unroll 1
  for(int e2=0;e2<32;e2++){
    const uint4* wr=(const uint4*)(lds+GWQ+e2*64);
    f16x2 ye=u2h(yp2[e2]);
    #pragma unroll
    for(int db=0;db<16;db++){
      uint4 w4=wr[db];
      rawq[4*db+0]=fdot2f(ye,u2h(w4.x),rawq[4*db+0]);
      rawq[4*db+1]=fdot2f(ye,u2h(w4.y),rawq[4*db+1]);
      rawq[4*db+2]=fdot2f(ye,u2h(w4.z),rawq[4*db+2]);
      rawq[4*db+3]=fdot2f(ye,u2h(w4.w),rawq[4*db+3]);
    }
  }
  unsigned rq2[32];
  float sc=0.125f*rstd;
  #pragma unroll
  for(int d2=0;d2<32;d2++) rq2[d2]=pk2(sc*rawq[2*d2],sc*rawq[2*d2+1]);
  // online softmax + PV, chunks of 16 j
  const float* cskf=(const float*)(lds+CSKo);
  const float* cnkf=(const float*)(lds+CNKo);
  float m=-1e30f, lsum=0.f;
  f16x2 o2[33];
  #pragma unroll
  for(int d2=0;d2<32;d2++) o2[d2]=u2h(0u);
  #pragma unroll 1
  for(int c=0;c<32;c++){
    float s[16];
    #pragma unroll
    for(int jj=0;jj<16;jj++){
      int j=c*16+jj;
      const uint4* kr=(const uint4*)(lds+KLS+j*32);
      float a0=0.f,a1=0.f,a2=0.f,a3=0.f;
      #pragma unroll
      for(int db=0;db<8;db++){
        uint4 k4=kr[db];
        a0=fdot2f(u2h(rq2[4*db+0]),u2h(k4.x),a0);
        a1=fdot2f(u2h(rq2[4*db+1]),u2h(k4.y),a1);
        a2=fdot2f(u2h(rq2[4*db+2]),u2h(k4.z),a2);
        a3=fdot2f(u2h(rq2[4*db+3]),u2h(k4.w),a3);
      }
      s[jj]=((a0+a1)+(a2+a3)) - rm*cskf[j] + cnkf[j];
    }
    float cm=s[0];
    #pragma unroll
    for(int jj=1;jj<16;jj++) cm=fmaxf(cm,s[jj]);
    float mnew=fmaxf(m,cm);
    float f=__expf(m-mnew);
    m=mnew;
    f16x2 fh; fh.x=fh.y=(_Float16)f;
    #pragma unroll
    for(int d2=0;d2<32;d2++) o2[d2]*=fh;
    lsum*=f;
    #pragma unroll
    for(int jj=0;jj<16;jj++){
      float p=__expf(s[jj]-mnew);
      lsum+=p;
      f16x2 ph; ph.x=ph.y=(_Float16)p;
      const uint4* vr=(const uint4*)(lds+VLS+(c*16+jj)*32);
      #pragma unroll
      for(int db=0;db<8;db++){
        uint4 v4=vr[db];
        o2[4*db+0]+=u2h(v4.x)*ph;
        o2[4*db+1]+=u2h(v4.y)*ph;
        o2[4*db+2]+=u2h(v4.z)*ph;
        o2[4*db+3]+=u2h(v4.w)*ph;
      }
    }
  }
  // normalize + out-projection (bo folded as row 32 with O=1)
  {
    float invl=1.f/lsum;
    f16x2 ih; ih.x=ih.y=(_Float16)invl;
    #pragma unroll
    for(int d2=0;d2<32;d2++) o2[d2]*=ih;
    o2[32]=u2h(pk2(1.f,0.f));
  }
  float acc[64];
  #pragma unroll
  for(int r=0;r<64;r++) acc[r]=0.f;
  #pragma unroll 1
  for(int d2=0;d2<33;d2++){
    const uint4* wr=(const uint4*)(lds+WOP+d2*64);
    f16x2 od=o2[d2];
    #pragma unroll
    for(int db=0;db<16;db++){
      uint4 w4=wr[db];
      acc[4*db+0]=fdot2f(od,u2h(w4.x),acc[4*db+0]);
      acc[4*db+1]=fdot2f(od,u2h(w4.y),acc[4*db+1]);
      acc[4*db+2]=fdot2f(od,u2h(w4.z),acc[4*db+2]);
      acc[4*db+3]=fdot2f(od,u2h(w4.w),acc[4*db+3]);
    }
  }
  float* orow=out+row*64;
  #pragma unroll
  for(int i=0;i<16;i++){
    float4 yv=((const float4*)yr)[i];
    float4 st;
    st.x=acc[4*i+0]+yv.x; st.y=acc[4*i+1]+yv.y;
    st.z=acc[4*i+2]+yv.z; st.w=acc[4*i+3]+yv.w;
    ((float4*)orow)[i]=st;
  }
}

// ---------------- Part B2: decoder FF, point-per-lane, in place on d_out ----------------
// grid 512 x 512
__global__ void __launch_bounds__(512,1) k_ffq2(
    float* __restrict__ y, const float* __restrict__ ng, const float* __restrict__ nb,
    const float* __restrict__ w1, const float* __restrict__ b1,
    const float* __restrict__ w2, const float* __restrict__ b2){
  __shared__ __align__(16) unsigned gw1p[4096];   // [c=128][e2=32] g-folded w1 pairs over e
  __shared__ __align__(16) unsigned w2p[2112];    // [d2=33][r=64]; row 32 = (b2_r,0)
  __shared__ float cs1f[128], cn1f[128];
  int tid=threadIdx.x;
  for(int idx=tid;idx<4096;idx+=512){
    int cc=idx>>5, e2=idx&31;
    gw1p[idx]=pk2(ng[2*e2]*w1[(2*e2)*128+cc], ng[2*e2+1]*w1[(2*e2+1)*128+cc]);
  }
  for(int idx=tid;idx<2112;idx+=512){
    int d2=idx>>6, r=idx&63;
    w2p[idx]=(d2<32)? pk2(w2[(2*d2)*64+r], w2[(2*d2+1)*64+r]) : pk2(b2[r],0.f);
  }
  if(tid<128){
    float cs=0.f, cn=0.f;
    for(int e=0;e<64;e++){ float wv=w1[e*128+tid]; cs+=ng[e]*wv; cn+=nb[e]*wv; }
    cs1f[tid]=cs; cn1f[tid]=cn+b1[tid];
  }
  __syncthreads();
  size_t row=(size_t)blockIdx.x*512 + tid;
  float* yrow=y+row*64;
  float ysum=0.f, ysq=0.f;
  unsigned yp2[32];
  {
    float4 yv[16];
    #pragma unroll
    for(int i=0;i<16;i++){
      yv[i]=((const float4*)yrow)[i];
      ysum += (yv[i].x+yv[i].y)+(yv[i].z+yv[i].w);
      ysq  += yv[i].x*yv[i].x+yv[i].y*yv[i].y+yv[i].z*yv[i].z+yv[i].w*yv[i].w;
    }
    float mean=ysum*(1.f/64.f);
    float rstd=rsqrtf(ysq*(1.f/64.f)-mean*mean+1e-5f);
    float rm=rstd*mean;
    #pragma unroll
    for(int i=0;i<16;i++){
      yp2[2*i]  =pk2(rstd*yv[i].x,rstd*yv[i].y);
      yp2[2*i+1]=pk2(rstd*yv[i].z,rstd*yv[i].w);
    }
    // stash rm in ysum for later use
    ysum=rm;
  }
  float rm=ysum;
  // GEGLU: u_c = h_c * gelu(h_{c+64}), h in LN-folded form
  unsigned u2[33];
  #pragma unroll 1
  for(int c=0;c<64;c+=2){
    float uu[2];
    #pragma unroll
    for(int k=0;k<2;k++){
      int cc=c+k;
      const uint4* wa=(const uint4*)&gw1p[cc*32];
      const uint4* wg=(const uint4*)&gw1p[(cc+64)*32];
      float a0=0.f,a1=0.f,g0=0.f,g1=0.f;
      #pragma unroll
      for(int db=0;db<8;db++){
        uint4 A=wa[db], G=wg[db];
        a0=fdot2f(u2h(yp2[4*db+0]),u2h(A.x),a0);
        a1=fdot2f(u2h(yp2[4*db+1]),u2h(A.y),a1);
        a0=fdot2f(u2h(yp2[4*db+2]),u2h(A.z),a0);
        a1=fdot2f(u2h(yp2[4*db+3]),u2h(A.w),a1);
        g0=fdot2f(u2h(yp2[4*db+0]),u2h(G.x),g0);
        g1=fdot2f(u2h(yp2[4*db+1]),u2h(G.y),g1);
        g0=fdot2f(u2h(yp2[4*db+2]),u2h(G.z),g0);
        g1=fdot2f(u2h(yp2[4*db+3]),u2h(G.w),g1);
      }
      float ha=(a0+a1)-rm*cs1f[cc]+cn1f[cc];
      float hg=(g0+g1)-rm*cs1f[cc+64]+cn1f[cc+64];
      uu[k]=ha*gelu_exact(hg);
    }
    u2[c>>1]=pk2(uu[0],uu[1]);
  }
  u2[32]=pk2(1.f,0.f);
  float acc[64];
  #pragma unroll
  for(int r=0;r<64;r++) acc[r]=0.f;
  #pragma unroll 1
  for(int d2=0;d2<33;d2++){
    const uint4* wr=(const uint4*)&w2p[d2*64];
    f16x2 ud=u2h(u2[d2]);
    #pragma unroll
    for(int db=0;db<16;db++){
      uint4 w4=wr[db];
      acc[4*db+0]=fdot2f(ud,u2h(w4.x),acc[4*db+0]);
      acc[4*db+1]=fdot2f(ud,u2h(w4.y),acc[4*db+1]);
      acc[4*db+2]=fdot2f(ud,u2h(w4.z),acc[4*db+2]);
      acc[4*db+3]=fdot2f(ud,u2h(w4.w),acc[4*db+3]);
    }
  }
  #pragma unroll
  for(int i=0;i<16;i++){
    float4 yv=((const float4*)yrow)[i];
    float4 st;
    st.x=acc[4*i+0]+yv.x; st.y=acc[4*i+1]+yv.y;
    st.z=acc[4*i+2]+yv.z; st.w=acc[4*i+3]+yv.w;
    ((float4*)yrow)[i]=st;
  }
}

extern "C" void kernel_launch(void* const* d_in, const int* in_sizes, int n_in,
                              void* d_out, int out_size, void* d_ws, size_t ws_size,
                              hipStream_t stream){
  const float* cb      =(const float*)d_in[0];
  const float* queries =(const float*)d_in[1];
  const float* latents =(const float*)d_in[2];
  const float* ca_ng=(const float*)d_in[3],  *ca_nb=(const float*)d_in[4];
  const float* ca_cng=(const float*)d_in[5], *ca_cnb=(const float*)d_in[6];
  const float* ca_wq=(const float*)d_in[7],  *ca_wkv=(const float*)d_in[8];
  const float* ca_wo=(const float*)d_in[9],  *ca_bo=(const float*)d_in[10];
  const float* cf_ng=(const float*)d_in[11], *cf_nb=(const float*)d_in[12];
  const float* cf_w1=(const float*)d_in[13], *cf_b1=(const float*)d_in[14];
  const float* cf_w2=(const float*)d_in[15], *cf_b2=(const float*)d_in[16];
  const float* sa_ng=(const float*)d_in[17], *sa_nb=(const float*)d_in[18];
  const float* sa_wq=(const float*)d_in[19], *sa_wkv=(const float*)d_in[20];
  const float* sa_wo=(const float*)d_in[21], *sa_bo=(const float*)d_in[22];
  const float* sf_ng=(const float*)d_in[23], *sf_nb=(const float*)d_in[24];
  const float* sf_w1=(const float*)d_in[25], *sf_b1=(const float*)d_in[26];
  const float* sf_w2=(const float*)d_in[27], *sf_b2=(const float*)d_in[28];
  const float* qa_ng=(const float*)d_in[29], *qa_nb=(const float*)d_in[30];
  const float* qa_cng=(const float*)d_in[31],*qa_cnb=(const float*)d_in[32];
  const float* qa_wq=(const float*)d_in[33], *qa_wkv=(const float*)d_in[34];
  const float* qa_wo=(const float*)d_in[35], *qa_bo=(const float*)d_in[36];
  const float* qf_ng=(const float*)d_in[37], *qf_nb=(const float*)d_in[38];
  const float* qf_w1=(const float*)d_in[39], *qf_b1=(const float*)d_in[40];
  const float* qf_w2=(const float*)d_in[41], *qf_b2=(const float*)d_in[42];
  float* out=(float*)d_out;

  // Part-A scratch lives inside d_out (all overwritten by k_coord_pt + k_ffq2).
  float* kcb = out;                 // 262144
  float* vcb = kcb + 262144;        // 262144
  float* q1  = vcb + 262144;        // 32768
  float* x1  = q1  + 32768;         // 262144
  float* x2  = x1  + 262144;        // 262144
  float* x3  = x2  + 262144;        // 262144
  float* lat = x3  + 262144;        // 262144
  float* saq = lat + 262144;        // 1048576
  float* sak = saq + 1048576;       // 1048576
  float* sav = sak + 1048576;       // 1048576
  float* sao = sav + 1048576;       // 1048576 -> total 5,799,936 < 16,777,216

  // kp/vp survive into k_coord_pt (which overwrites d_out): keep in d_ws (512 KB).
  unsigned* kp=(unsigned*)d_ws;     // 65536 u32
  unsigned* vp=kp+65536;            // 65536 u32

  k_cb_kv<<<4096,128,0,stream>>>(cb,ca_cng,ca_cnb,ca_wkv,kcb,vcb);
  k_lat_q<<<512,64,0,stream>>>(latents,ca_ng,ca_nb,ca_wq,q1);
  k_attn1<<<dim3(512,4),64,0,stream>>>(q1,kcb,vcb,ca_wo,ca_bo,latents,x1);
  k_ffn<<<2048,256,0,stream>>>(x1,cf_ng,cf_nb,cf_w1,cf_b1,cf_w2,cf_b2,x2);
  k_sa_qkv<<<2048,256,0,stream>>>(x2,sa_ng,sa_nb,sa_wq,sa_wkv,saq,sak,sav);
  k_sa_attn<<<dim3(128,8,4),256,0,stream>>>(saq,sak,sav,sao);
  k_sa_proj<<<2048,256,0,stream>>>(sao,sa_wo,sa_bo,x2,x3);
  k_ffn<<<2048,256,0,stream>>>(x3,sf_ng,sf_nb,sf_w1,sf_b1,sf_w2,sf_b2,lat);
  k_kv2p<<<2048,128,0,stream>>>(lat,qa_cng,qa_cnb,qa_wkv,kp,vp);
  hipFuncSetAttribute((const void*)k_coord_pt,
                      hipFuncAttributeMaxDynamicSharedMemorySize, LDSU32*4);
  k_coord_pt<<<512,512,LDSU32*4,stream>>>(queries,kp,vp,qa_ng,qa_nb,qa_wq,qa_wo,qa_bo,out);
  k_ffq2<<<512,512,0,stream>>>(out,qf_ng,qf_nb,qf_w1,qf_b1,qf_w2,qf_b2);
}

// Round 5
// 1684.868 us; speedup vs baseline: 3.1890x; 1.0748x over previous
//
#include <hip/hip_runtime.h>
#include <hip/hip_fp16.h>
#include <math.h>

#define DEV __device__ __forceinline__

typedef _Float16 f16x2 __attribute__((ext_vector_type(2)));

DEV float wsumf(float v){
  #pragma unroll
  for(int m=32;m>=1;m>>=1) v += __shfl_xor(v,m,64);
  return v;
}
DEV float wmaxf(float v){
  #pragma unroll
  for(int m=32;m>=1;m>>=1) v = fmaxf(v,__shfl_xor(v,m,64));
  return v;
}
DEV unsigned pk2(float a, float b){
  f16x2 h; h.x=(_Float16)a; h.y=(_Float16)b;
  return __builtin_bit_cast(unsigned, h);
}
DEV f16x2 u2h(unsigned u){ return __builtin_bit_cast(f16x2, u); }
DEV float fdot2f(f16x2 a, f16x2 b, float c){
#if __has_builtin(__builtin_amdgcn_fdot2)
  return __builtin_amdgcn_fdot2(a,b,c,false);
#else
  return c + (float)a.x*(float)b.x + (float)a.y*(float)b.y;
#endif
}
DEV float gelu_exact(float g){ return 0.5f*g*(1.f+erff(g*0.70710678118654752f)); }

// ---------------- Part A: codebook attention stack (all fp32) ----------------

__global__ void k_cb_kv(const float* __restrict__ cb, const float* __restrict__ cng,
                        const float* __restrict__ cnb, const float* __restrict__ wkv,
                        float* __restrict__ kcb, float* __restrict__ vcb){
  int r = blockIdx.x;          // b*1024 + j
  int t = threadIdx.x;         // 128 threads
  __shared__ float cn[256]; __shared__ float red[4];
  const float* row = cb + (size_t)r*256;
  float a0 = row[t], a1 = row[t+128];
  float s = wsumf(a0+a1), ss = wsumf(a0*a0+a1*a1);
  int w = t>>6;
  if ((t&63)==0){ red[w] = s; red[2+w] = ss; }
  __syncthreads();
  float mean = (red[0]+red[1])*(1.f/256.f);
  float var  = (red[2]+red[3])*(1.f/256.f) - mean*mean;
  float rstd = rsqrtf(var + 1e-5f);
  cn[t]     = (a0-mean)*rstd*cng[t]+cnb[t];
  cn[t+128] = (a1-mean)*rstd*cng[t+128]+cnb[t+128];
  __syncthreads();
  float acc = 0.f;
  for(int d=0; d<256; d++) acc += cn[d]*wkv[d*128+t];
  if (t<64) kcb[(size_t)r*64 + t] = acc;
  else      vcb[(size_t)r*64 + (t-64)] = acc;
}

__global__ void k_lat_q(const float* __restrict__ latents, const float* __restrict__ ng,
                        const float* __restrict__ nb, const float* __restrict__ wq,
                        float* __restrict__ q1){
  int i = blockIdx.x; int l = threadIdx.x;
  __shared__ float xn[128];
  float a0 = latents[i*128+l], a1 = latents[i*128+64+l];
  float s = wsumf(a0+a1), ss = wsumf(a0*a0+a1*a1);
  float mean = s*(1.f/128.f), var = ss*(1.f/128.f) - mean*mean;
  float rstd = rsqrtf(var+1e-5f);
  xn[l]    = (a0-mean)*rstd*ng[l]+nb[l];
  xn[64+l] = (a1-mean)*rstd*ng[64+l]+nb[64+l];
  __syncthreads();
  float acc=0.f;
  for(int d=0; d<128; d++) acc += xn[d]*wq[d*64+l];
  q1[i*64+l] = acc*0.125f;
}

// cross attention 1 + out proj + residual -> x1   grid (512,4) x 256
__global__ void k_attn1(const float* __restrict__ q1, const float* __restrict__ kcb,
                        const float* __restrict__ vcb, const float* __restrict__ wo,
                        const float* __restrict__ bo, const float* __restrict__ latents,
                        float* __restrict__ x1){
  int b = blockIdx.y, i = blockIdx.x, t = threadIdx.x;
  int l = t&63, w = t>>6;
  __shared__ float qs[64], as[1024], red[4][64], redm[4], reds[4], os[64];
  if(t<64) qs[t] = q1[i*64+t];
  __syncthreads();
  const float* kb = kcb + (size_t)b*65536;
  float s[4];
  #pragma unroll
  for(int tt=0;tt<4;tt++){
    int j = t + 256*tt; float acc=0.f;
    const float* kr = kb + (size_t)j*64;
    for(int d=0;d<64;d++) acc += qs[d]*kr[d];
    s[tt]=acc;
  }
  float m = fmaxf(fmaxf(s[0],s[1]),fmaxf(s[2],s[3]));
  m = wmaxf(m);
  if(l==0) redm[w]=m;
  __syncthreads();
  m = fmaxf(fmaxf(redm[0],redm[1]),fmaxf(redm[2],redm[3]));
  float sum=0.f;
  #pragma unroll
  for(int tt=0;tt<4;tt++){ s[tt]=__expf(s[tt]-m); sum+=s[tt]; }
  sum = wsumf(sum);
  if(l==0) reds[w]=sum;
  __syncthreads();
  sum = reds[0]+reds[1]+reds[2]+reds[3];
  float inv = 1.f/sum;
  #pragma unroll
  for(int tt=0;tt<4;tt++) as[t+256*tt] = s[tt]*inv;
  __syncthreads();
  const float* vb = vcb + (size_t)b*65536;
  float o=0.f;
  for(int j=256*w;j<256*w+256;j++) o += as[j]*vb[(size_t)j*64+l];
  red[w][l]=o;
  __syncthreads();
  if(t<64) os[t]=red[0][t]+red[1][t]+red[2][t]+red[3][t];
  __syncthreads();
  if(t<128){
    float r = bo[t] + latents[i*128+t];
    for(int d=0;d<64;d++) r += os[d]*wo[d*128+t];
    x1[((size_t)b*512+i)*128+t] = r;
  }
}

__global__ void k_ffn(const float* __restrict__ xin, const float* __restrict__ ng,
                      const float* __restrict__ nb, const float* __restrict__ w1,
                      const float* __restrict__ b1, const float* __restrict__ w2,
                      const float* __restrict__ b2, float* __restrict__ xout){
  int r = blockIdx.x; int t = threadIdx.x;
  __shared__ float xi[128], h[128], tf[1024], red[8];
  const float* row = xin + (size_t)r*128;
  float a = (t<128)? row[t] : 0.f;
  float s=wsumf(a), ss=wsumf(a*a);
  int w=t>>6;
  if((t&63)==0){red[w]=s; red[4+w]=ss;}
  __syncthreads();
  float mean=(red[0]+red[1]+red[2]+red[3])*(1.f/128.f);
  float var =(red[4]+red[5]+red[6]+red[7])*(1.f/128.f) - mean*mean;
  float rstd=rsqrtf(var+1e-5f);
  if(t<128){ xi[t]=a; h[t]=(a-mean)*rstd*ng[t]+nb[t]; }
  __syncthreads();
  for(int c=t;c<1024;c+=256){
    float acc=b1[c];
    for(int d=0;d<128;d++) acc+=h[d]*w1[d*1024+c];
    tf[c]=acc;
  }
  __syncthreads();
  for(int c=t;c<512;c+=256){
    tf[c] = tf[c]*gelu_exact(tf[512+c]);
  }
  __syncthreads();
  if(t<128){
    float acc=b2[t];
    for(int d=0;d<512;d++) acc+=tf[d]*w2[d*128+t];
    xout[(size_t)r*128+t] = acc + xi[t];
  }
}

__global__ void k_sa_qkv(const float* __restrict__ xin, const float* __restrict__ ng,
                         const float* __restrict__ nb, const float* __restrict__ wq,
                         const float* __restrict__ wkv, float* __restrict__ saq,
                         float* __restrict__ sak, float* __restrict__ sav){
  int r=blockIdx.x, t=threadIdx.x;
  __shared__ float h[128], red[8];
  const float* row = xin + (size_t)r*128;
  float a = (t<128)? row[t]:0.f;
  float s=wsumf(a), ss=wsumf(a*a);
  int w=t>>6;
  if((t&63)==0){red[w]=s; red[4+w]=ss;}
  __syncthreads();
  float mean=(red[0]+red[1]+red[2]+red[3])*(1.f/128.f);
  float var =(red[4]+red[5]+red[6]+red[7])*(1.f/128.f)-mean*mean;
  float rstd=rsqrtf(var+1e-5f);
  if(t<128) h[t]=(a-mean)*rstd*ng[t]+nb[t];
  __syncthreads();
  for(int c=t;c<512;c+=256){
    float aq=0.f, ak=0.f, av=0.f;
    for(int d=0;d<128;d++){
      float hd=h[d];
      aq += hd*wq[d*512+c];
      ak += hd*wkv[d*1024+c];
      av += hd*wkv[d*1024+512+c];
    }
    size_t o=(size_t)r*512+c;
    saq[o]=aq*0.125f; sak[o]=ak; sav[o]=av;
  }
}

__global__ void k_sa_attn(const float* __restrict__ saq, const float* __restrict__ sak,
                          const float* __restrict__ sav, float* __restrict__ sao){
  int b=blockIdx.z, hh=blockIdx.y;
  int w=threadIdx.x>>6, l=threadIdx.x&63;
  int i=blockIdx.x*4+w;
  __shared__ float qs[4][64]; __shared__ float as[4][512];
  qs[w][l]=saq[((size_t)b*512+i)*512+hh*64+l];
  __syncthreads();
  const float* kb = sak + (size_t)b*512*512 + hh*64;
  float s[8];
  #pragma unroll
  for(int t=0;t<8;t++){
    int j=l+64*t; const float* kr=kb+(size_t)j*512; float acc=0.f;
    for(int d=0;d<64;d++) acc+=qs[w][d]*kr[d];
    s[t]=acc;
  }
  float m=-1e30f;
  #pragma unroll
  for(int t=0;t<8;t++) m=fmaxf(m,s[t]);
  m=wmaxf(m);
  float sum=0.f;
  #pragma unroll
  for(int t=0;t<8;t++){ s[t]=__expf(s[t]-m); sum+=s[t]; }
  sum=wsumf(sum);
  float inv=1.f/sum;
  #pragma unroll
  for(int t=0;t<8;t++) as[w][l+64*t]=s[t]*inv;
  __syncthreads();
  const float* vb = sav + (size_t)b*512*512 + hh*64;
  float o=0.f;
  for(int j=0;j<512;j++) o += as[w][j]*vb[(size_t)j*512+l];
  sao[((size_t)b*512+i)*512+hh*64+l]=o;
}

__global__ void k_sa_proj(const float* __restrict__ sao, const float* __restrict__ wo,
                          const float* __restrict__ bo, const float* __restrict__ resid,
                          float* __restrict__ xout){
  int r=blockIdx.x, t=threadIdx.x;
  __shared__ float o[512]; __shared__ float acc2[256];
  o[t]=sao[(size_t)r*512+t]; o[256+t]=sao[(size_t)r*512+256+t];
  __syncthreads();
  int c = t&127; int half = t>>7;
  float acc=0.f;
  int d0 = half*256;
  for(int d=d0; d<d0+256; d++) acc += o[d]*wo[d*128+c];
  acc2[t]=acc; __syncthreads();
  if(t<128) xout[(size_t)r*128+t] = acc2[t]+acc2[t+128]+bo[t]+resid[(size_t)r*128+t];
}

// LN(lat) @ qa_wkv -> packed f16 kp, vp   grid 2048 x 128
__global__ void k_kv2p(const float* __restrict__ lat, const float* __restrict__ cng,
                       const float* __restrict__ cnb, const float* __restrict__ wkv,
                       unsigned* __restrict__ kp, unsigned* __restrict__ vp){
  int r=blockIdx.x, t=threadIdx.x;
  __shared__ float cn[128]; __shared__ float red[4]; __shared__ float kv[128];
  float a = lat[(size_t)r*128+t];
  float s=wsumf(a), ss=wsumf(a*a);
  int w=t>>6;
  if((t&63)==0){red[w]=s;red[2+w]=ss;}
  __syncthreads();
  float mean=(red[0]+red[1])*(1.f/128.f), var=(red[2]+red[3])*(1.f/128.f)-mean*mean;
  float rstd=rsqrtf(var+1e-5f);
  cn[t]=(a-mean)*rstd*cng[t]+cnb[t];
  __syncthreads();
  float acc=0.f;
  for(int d=0;d<128;d++) acc+=cn[d]*wkv[d*128+t];
  kv[t]=acc;
  __syncthreads();
  if(t<32)               kp[(size_t)r*32 + t]      = pk2(kv[2*t],      kv[2*t+1]);
  else if(t>=64 && t<96) vp[(size_t)r*32 + (t-64)] = pk2(kv[64+2*(t-64)], kv[64+2*(t-64)+1]);
}

// ---------------- Part B1: coordinate attention, 2 points per lane ----------------
// grid 256 x 512, dynamic LDS 152576 B. Each lane owns rows (blk*1024+tid) and (+512);
// all K/V/weight LDS reads are wave-uniform broadcasts shared by both points.
// j-chunk = 8 (was 16) to keep the unrolled body ~1.1k instr for compile/regalloc.
#define KLS 0        // [j=512][d2=32] f16x2 K pairs (over d)
#define VLS 16384    // [j=512][d2=32] f16x2 V pairs (over d)
#define GWQ 32768    // [e2=32][d=64]  f16x2 (g_e * wq[e][d]) pairs over e
#define WOP 34816    // [d2=33][r=64]  f16x2 wo pairs over d; row 32 = (bo_r, 0)
#define CSKo 36928   // [512] f32: 0.125 * (cs . K_j)
#define CNKo 37440   // [512] f32: 0.125 * (cn . K_j)
#define CSF 37952    // [64] f32 tmp
#define CNF 38016    // [64] f32 tmp
#define CS2 38080    // [32] f16x2 packed cs
#define CN2 38112    // [32] f16x2 packed cn
#define LDSU32 38144

#define COORD_EPI(OARR, LSUM, ROW) { \
  float invl=1.f/(LSUM); \
  f16x2 ih; ih.x=ih.y=(_Float16)invl; \
  _Pragma("unroll") \
  for(int d2=0;d2<32;d2++) OARR[d2]*=ih; \
  OARR[32]=u2h(pk2(1.f,0.f)); \
  float acc[64]; \
  _Pragma("unroll") \
  for(int r=0;r<64;r++) acc[r]=0.f; \
  _Pragma("unroll 1") \
  for(int d2=0;d2<33;d2++){ \
    const uint4* wr=(const uint4*)(lds+WOP+d2*64); \
    f16x2 od=OARR[d2]; \
    _Pragma("unroll") \
    for(int db=0;db<16;db++){ \
      uint4 w4=wr[db]; \
      acc[4*db+0]=fdot2f(od,u2h(w4.x),acc[4*db+0]); \
      acc[4*db+1]=fdot2f(od,u2h(w4.y),acc[4*db+1]); \
      acc[4*db+2]=fdot2f(od,u2h(w4.z),acc[4*db+2]); \
      acc[4*db+3]=fdot2f(od,u2h(w4.w),acc[4*db+3]); \
    } \
  } \
  const float* yrr=queries+(ROW)*64; \
  float* orow=out+(ROW)*64; \
  _Pragma("unroll") \
  for(int i=0;i<16;i++){ \
    float4 yv=((const float4*)yrr)[i]; \
    float4 st; \
    st.x=acc[4*i+0]+yv.x; st.y=acc[4*i+1]+yv.y; \
    st.z=acc[4*i+2]+yv.z; st.w=acc[4*i+3]+yv.w; \
    ((float4*)orow)[i]=st; \
  } }

__global__ void __launch_bounds__(512,1) k_coord_pt(
    const float* __restrict__ queries, const unsigned* __restrict__ kp_g,
    const unsigned* __restrict__ vp_g, const float* __restrict__ ng,
    const float* __restrict__ nb, const float* __restrict__ wq,
    const float* __restrict__ wo, const float* __restrict__ bo,
    float* __restrict__ out){
  extern __shared__ unsigned lds[];
  int tid=threadIdx.x;
  int b = blockIdx.x>>6;                       // 64 blocks per batch
  const unsigned* kg=kp_g+(size_t)b*16384;
  const unsigned* vg=vp_g+(size_t)b*16384;
  for(int idx=tid; idx<4096; idx+=512){
    ((uint4*)(lds+KLS))[idx]=((const uint4*)kg)[idx];
    ((uint4*)(lds+VLS))[idx]=((const uint4*)vg)[idx];
  }
  for(int idx=tid; idx<2048; idx+=512){
    int e2=idx>>6, d=idx&63;
    lds[GWQ+idx]=pk2(ng[2*e2]*wq[(2*e2)*64+d], ng[2*e2+1]*wq[(2*e2+1)*64+d]);
  }
  for(int idx=tid; idx<2112; idx+=512){
    int d2=idx>>6, r=idx&63;
    lds[WOP+idx]=(d2<32)? pk2(wo[(2*d2)*64+r], wo[(2*d2+1)*64+r]) : pk2(bo[r],0.f);
  }
  if(tid<64){
    float cs=0.f, cn=0.f;
    for(int e=0;e<64;e++){ float wv=wq[e*64+tid]; cs+=ng[e]*wv; cn+=nb[e]*wv; }
    ((float*)(lds+CSF))[tid]=cs; ((float*)(lds+CNF))[tid]=cn;
  }
  __syncthreads();
  if(tid<32){
    const float* csf=(const float*)(lds+CSF); const float* cnf=(const float*)(lds+CNF);
    lds[CS2+tid]=pk2(csf[2*tid],csf[2*tid+1]);
    lds[CN2+tid]=pk2(cnf[2*tid],cnf[2*tid+1]);
  }
  __syncthreads();
  { // per-j constants: csk_j = 0.125*(cs.K_j), cnk_j = 0.125*(cn.K_j); tid = j
    float a=0.f, c=0.f;
    #pragma unroll 1
    for(int d2=0; d2<32; d2++){
      f16x2 kk=u2h(lds[KLS + tid*32 + d2]);
      a=fdot2f(u2h(lds[CS2+d2]),kk,a);
      c=fdot2f(u2h(lds[CN2+d2]),kk,c);
    }
    ((float*)(lds+CSKo))[tid]=0.125f*a;
    ((float*)(lds+CNKo))[tid]=0.125f*c;
  }
  __syncthreads();

  // ---- two points per lane ----
  size_t row0=(size_t)blockIdx.x*1024 + tid;   // second point: row0+512
  float rm[2];
  unsigned rq2[2][32];
  #pragma unroll
  for(int p=0;p<2;p++){
    const float* yr=queries+(row0+(size_t)p*512)*64;
    float ysum=0.f, ysq=0.f;
    unsigned yp2[32];
    {
      float4 yv[16];
      #pragma unroll
      for(int i=0;i<16;i++){
        yv[i]=((const float4*)yr)[i];
        ysum += (yv[i].x+yv[i].y)+(yv[i].z+yv[i].w);
        ysq  += yv[i].x*yv[i].x+yv[i].y*yv[i].y+yv[i].z*yv[i].z+yv[i].w*yv[i].w;
      }
      #pragma unroll
      for(int i=0;i<16;i++){
        yp2[2*i]  =pk2(yv[i].x,yv[i].y);
        yp2[2*i+1]=pk2(yv[i].z,yv[i].w);
      }
    }
    float mean=ysum*(1.f/64.f);
    float rstd=rsqrtf(ysq*(1.f/64.f)-mean*mean+1e-5f);
    rm[p]=rstd*mean;
    float rawq[64];
    #pragma unroll
    for(int d=0;d<64;d++) rawq[d]=0.f;
    #pragma unroll 1
    for(int e2=0;e2<32;e2++){
      const uint4* wr=(const uint4*)(lds+GWQ+e2*64);
      f16x2 ye=u2h(yp2[e2]);
      #pragma unroll
      for(int db=0;db<16;db++){
        uint4 w4=wr[db];
        rawq[4*db+0]=fdot2f(ye,u2h(w4.x),rawq[4*db+0]);
        rawq[4*db+1]=fdot2f(ye,u2h(w4.y),rawq[4*db+1]);
        rawq[4*db+2]=fdot2f(ye,u2h(w4.z),rawq[4*db+2]);
        rawq[4*db+3]=fdot2f(ye,u2h(w4.w),rawq[4*db+3]);
      }
    }
    float sc=0.125f*rstd;
    #pragma unroll
    for(int d2=0;d2<32;d2++) rq2[p][d2]=pk2(sc*rawq[2*d2],sc*rawq[2*d2+1]);
  }

  const float* cskf=(const float*)(lds+CSKo);
  const float* cnkf=(const float*)(lds+CNKo);
  float m0=-1e30f, m1=-1e30f, ls0=0.f, ls1=0.f;
  f16x2 oA[33], oB[33];
  #pragma unroll
  for(int d2=0;d2<32;d2++){ oA[d2]=u2h(0u); oB[d2]=u2h(0u); }
  #pragma unroll 1
  for(int c=0;c<64;c++){               // 64 chunks of 8 j
    float s0[8], s1[8];
    #pragma unroll
    for(int jj=0;jj<8;jj++){
      int j=c*8+jj;
      const uint4* kr=(const uint4*)(lds+KLS+j*32);
      float a0=0.f,a1=0.f,b0=0.f,b1=0.f;
      #pragma unroll
      for(int db=0;db<8;db++){
        uint4 k4=kr[db];
        a0=fdot2f(u2h(rq2[0][4*db+0]),u2h(k4.x),a0);
        a0=fdot2f(u2h(rq2[0][4*db+1]),u2h(k4.y),a0);
        a1=fdot2f(u2h(rq2[0][4*db+2]),u2h(k4.z),a1);
        a1=fdot2f(u2h(rq2[0][4*db+3]),u2h(k4.w),a1);
        b0=fdot2f(u2h(rq2[1][4*db+0]),u2h(k4.x),b0);
        b0=fdot2f(u2h(rq2[1][4*db+1]),u2h(k4.y),b0);
        b1=fdot2f(u2h(rq2[1][4*db+2]),u2h(k4.z),b1);
        b1=fdot2f(u2h(rq2[1][4*db+3]),u2h(k4.w),b1);
      }
      s0[jj]=(a0+a1) - rm[0]*cskf[j] + cnkf[j];
      s1[jj]=(b0+b1) - rm[1]*cskf[j] + cnkf[j];
    }
    // softmax update point 0
    {
      float cm=s0[0];
      #pragma unroll
      for(int jj=1;jj<8;jj++) cm=fmaxf(cm,s0[jj]);
      float mn=fmaxf(m0,cm);
      float f=__expf(m0-mn); m0=mn;
      f16x2 fh; fh.x=fh.y=(_Float16)f;
      #pragma unroll
      for(int d2=0;d2<32;d2++) oA[d2]*=fh;
      ls0*=f;
      #pragma unroll
      for(int jj=0;jj<8;jj++){ s0[jj]=__expf(s0[jj]-mn); ls0+=s0[jj]; }
    }
    // softmax update point 1
    {
      float cm=s1[0];
      #pragma unroll
      for(int jj=1;jj<8;jj++) cm=fmaxf(cm,s1[jj]);
      float mn=fmaxf(m1,cm);
      float f=__expf(m1-mn); m1=mn;
      f16x2 fh; fh.x=fh.y=(_Float16)f;
      #pragma unroll
      for(int d2=0;d2<32;d2++) oB[d2]*=fh;
      ls1*=f;
      #pragma unroll
      for(int jj=0;jj<8;jj++){ s1[jj]=__expf(s1[jj]-mn); ls1+=s1[jj]; }
    }
    // PV with shared V reads
    #pragma unroll
    for(int jj=0;jj<8;jj++){
      const uint4* vr=(const uint4*)(lds+VLS+(c*8+jj)*32);
      f16x2 p0; p0.x=p0.y=(_Float16)s0[jj];
      f16x2 p1; p1.x=p1.y=(_Float16)s1[jj];
      #pragma unroll
      for(int db=0;db<8;db++){
        uint4 v4=vr[db];
        oA[4*db+0]+=u2h(v4.x)*p0;  oB[4*db+0]+=u2h(v4.x)*p1;
        oA[4*db+1]+=u2h(v4.y)*p0;  oB[4*db+1]+=u2h(v4.y)*p1;
        oA[4*db+2]+=u2h(v4.z)*p0;  oB[4*db+2]+=u2h(v4.z)*p1;
        oA[4*db+3]+=u2h(v4.w)*p0;  oB[4*db+3]+=u2h(v4.w)*p1;
      }
    }
  }
  COORD_EPI(oA, ls0, row0)
  COORD_EPI(oB, ls1, row0+512)
}

// ---------------- Part B2: decoder FF, 2 points per lane, in place on d_out ----------------
// grid 256 x 512
#define FFQ_EPI(UARR, ROW) { \
  float acc[64]; \
  _Pragma("unroll") \
  for(int r=0;r<64;r++) acc[r]=0.f; \
  _Pragma("unroll 1") \
  for(int d2=0;d2<33;d2++){ \
    const uint4* wr=(const uint4*)&w2p[d2*64]; \
    f16x2 ud=u2h(UARR[d2]); \
    _Pragma("unroll") \
    for(int db=0;db<16;db++){ \
      uint4 w4=wr[db]; \
      acc[4*db+0]=fdot2f(ud,u2h(w4.x),acc[4*db+0]); \
      acc[4*db+1]=fdot2f(ud,u2h(w4.y),acc[4*db+1]); \
      acc[4*db+2]=fdot2f(ud,u2h(w4.z),acc[4*db+2]); \
      acc[4*db+3]=fdot2f(ud,u2h(w4.w),acc[4*db+3]); \
    } \
  } \
  float* yrw=y+(ROW)*64; \
  _Pragma("unroll") \
  for(int i=0;i<16;i++){ \
    float4 yv=((const float4*)yrw)[i]; \
    float4 st; \
    st.x=acc[4*i+0]+yv.x; st.y=acc[4*i+1]+yv.y; \
    st.z=acc[4*i+2]+yv.z; st.w=acc[4*i+3]+yv.w; \
    ((float4*)yrw)[i]=st; \
  } }

__global__ void __launch_bounds__(512,1) k_ffq2(
    float* __restrict__ y, const float* __restrict__ ng, const float* __restrict__ nb,
    const float* __restrict__ w1, const float* __restrict__ b1,
    const float* __restrict__ w2, const float* __restrict__ b2){
  __shared__ __align__(16) unsigned gw1p[4096];   // [c=128][e2=32] g-folded w1 pairs over e
  __shared__ __align__(16) unsigned w2p[2112];    // [d2=33][r=64]; row 32 = (b2_r,0)
  __shared__ float cs1f[128], cn1f[128];
  int tid=threadIdx.x;
  for(int idx=tid;idx<4096;idx+=512){
    int cc=idx>>5, e2=idx&31;
    gw1p[idx]=pk2(ng[2*e2]*w1[(2*e2)*128+cc], ng[2*e2+1]*w1[(2*e2+1)*128+cc]);
  }
  for(int idx=tid;idx<2112;idx+=512){
    int d2=idx>>6, r=idx&63;
    w2p[idx]=(d2<32)? pk2(w2[(2*d2)*64+r], w2[(2*d2+1)*64+r]) : pk2(b2[r],0.f);
  }
  if(tid<128){
    float cs=0.f, cn=0.f;
    for(int e=0;e<64;e++){ float wv=w1[e*128+tid]; cs+=ng[e]*wv; cn+=nb[e]*wv; }
    cs1f[tid]=cs; cn1f[tid]=cn+b1[tid];
  }
  __syncthreads();
  size_t row0=(size_t)blockIdx.x*1024 + tid;
  unsigned yp2[2][32];
  float rm[2];
  #pragma unroll
  for(int p=0;p<2;p++){
    const float* yrow=y+(row0+(size_t)p*512)*64;
    float ysum=0.f, ysq=0.f;
    float4 yv[16];
    #pragma unroll
    for(int i=0;i<16;i++){
      yv[i]=((const float4*)yrow)[i];
      ysum += (yv[i].x+yv[i].y)+(yv[i].z+yv[i].w);
      ysq  += yv[i].x*yv[i].x+yv[i].y*yv[i].y+yv[i].z*yv[i].z+yv[i].w*yv[i].w;
    }
    float mean=ysum*(1.f/64.f);
    float rstd=rsqrtf(ysq*(1.f/64.f)-mean*mean+1e-5f);
    rm[p]=rstd*mean;
    #pragma unroll
    for(int i=0;i<16;i++){
      yp2[p][2*i]  =pk2(rstd*yv[i].x,rstd*yv[i].y);
      yp2[p][2*i+1]=pk2(rstd*yv[i].z,rstd*yv[i].w);
    }
  }
  unsigned uA[33], uB[33];
  #pragma unroll 1
  for(int c=0;c<64;c+=2){
    float u0[2], u1[2];
    #pragma unroll
    for(int k=0;k<2;k++){
      int cc=c+k;
      const uint4* wa=(const uint4*)&gw1p[cc*32];
      const uint4* wg=(const uint4*)&gw1p[(cc+64)*32];
      float a0=0.f,g0=0.f,a1=0.f,g1=0.f;
      #pragma unroll
      for(int db=0;db<8;db++){
        uint4 A=wa[db], G=wg[db];
        a0=fdot2f(u2h(yp2[0][4*db+0]),u2h(A.x),a0);
        a0=fdot2f(u2h(yp2[0][4*db+1]),u2h(A.y),a0);
        a0=fdot2f(u2h(yp2[0][4*db+2]),u2h(A.z),a0);
        a0=fdot2f(u2h(yp2[0][4*db+3]),u2h(A.w),a0);
        g0=fdot2f(u2h(yp2[0][4*db+0]),u2h(G.x),g0);
        g0=fdot2f(u2h(yp2[0][4*db+1]),u2h(G.y),g0);
        g0=fdot2f(u2h(yp2[0][4*db+2]),u2h(G.z),g0);
        g0=fdot2f(u2h(yp2[0][4*db+3]),u2h(G.w),g0);
        a1=fdot2f(u2h(yp2[1][4*db+0]),u2h(A.x),a1);
        a1=fdot2f(u2h(yp2[1][4*db+1]),u2h(A.y),a1);
        a1=fdot2f(u2h(yp2[1][4*db+2]),u2h(A.z),a1);
        a1=fdot2f(u2h(yp2[1][4*db+3]),u2h(A.w),a1);
        g1=fdot2f(u2h(yp2[1][4*db+0]),u2h(G.x),g1);
        g1=fdot2f(u2h(yp2[1][4*db+1]),u2h(G.y),g1);
        g1=fdot2f(u2h(yp2[1][4*db+2]),u2h(G.z),g1);
        g1=fdot2f(u2h(yp2[1][4*db+3]),u2h(G.w),g1);
      }
      float ha0=a0-rm[0]*cs1f[cc]+cn1f[cc];
      float hg0=g0-rm[0]*cs1f[cc+64]+cn1f[cc+64];
      float ha1=a1-rm[1]*cs1f[cc]+cn1f[cc];
      float hg1=g1-rm[1]*cs1f[cc+64]+cn1f[cc+64];
      u0[k]=ha0*gelu_exact(hg0);
      u1[k]=ha1*gelu_exact(hg1);
    }
    uA[c>>1]=pk2(u0[0],u0[1]);
    uB[c>>1]=pk2(u1[0],u1[1]);
  }
  uA[32]=pk2(1.f,0.f);
  uB[32]=pk2(1.f,0.f);
  FFQ_EPI(uA, row0)
  FFQ_EPI(uB, row0+512)
}

extern "C" void kernel_launch(void* const* d_in, const int* in_sizes, int n_in,
                              void* d_out, int out_size, void* d_ws, size_t ws_size,
                              hipStream_t stream){
  const float* cb      =(const float*)d_in[0];
  const float* queries =(const float*)d_in[1];
  const float* latents =(const float*)d_in[2];
  const float* ca_ng=(const float*)d_in[3],  *ca_nb=(const float*)d_in[4];
  const float* ca_cng=(const float*)d_in[5], *ca_cnb=(const float*)d_in[6];
  const float* ca_wq=(const float*)d_in[7],  *ca_wkv=(const float*)d_in[8];
  const float* ca_wo=(const float*)d_in[9],  *ca_bo=(const float*)d_in[10];
  const float* cf_ng=(const float*)d_in[11], *cf_nb=(const float*)d_in[12];
  const float* cf_w1=(const float*)d_in[13], *cf_b1=(const float*)d_in[14];
  const float* cf_w2=(const float*)d_in[15], *cf_b2=(const float*)d_in[16];
  const float* sa_ng=(const float*)d_in[17], *sa_nb=(const float*)d_in[18];
  const float* sa_wq=(const float*)d_in[19], *sa_wkv=(const float*)d_in[20];
  const float* sa_wo=(const float*)d_in[21], *sa_bo=(const float*)d_in[22];
  const float* sf_ng=(const float*)d_in[23], *sf_nb=(const float*)d_in[24];
  const float* sf_w1=(const float*)d_in[25], *sf_b1=(const float*)d_in[26];
  const float* sf_w2=(const float*)d_in[27], *sf_b2=(const float*)d_in[28];
  const float* qa_ng=(const float*)d_in[29], *qa_nb=(const float*)d_in[30];
  const float* qa_cng=(const float*)d_in[31],*qa_cnb=(const float*)d_in[32];
  const float* qa_wq=(const float*)d_in[33], *qa_wkv=(const float*)d_in[34];
  const float* qa_wo=(const float*)d_in[35], *qa_bo=(const float*)d_in[36];
  const float* qf_ng=(const float*)d_in[37], *qf_nb=(const float*)d_in[38];
  const float* qf_w1=(const float*)d_in[39], *qf_b1=(const float*)d_in[40];
  const float* qf_w2=(const float*)d_in[41], *qf_b2=(const float*)d_in[42];
  float* out=(float*)d_out;

  // Part-A scratch lives inside d_out (all overwritten by k_coord_pt + k_ffq2).
  float* kcb = out;                 // 262144
  float* vcb = kcb + 262144;        // 262144
  float* q1  = vcb + 262144;        // 32768
  float* x1  = q1  + 32768;         // 262144
  float* x2  = x1  + 262144;        // 262144
  float* x3  = x2  + 262144;        // 262144
  float* lat = x3  + 262144;        // 262144
  float* saq = lat + 262144;        // 1048576
  float* sak = saq + 1048576;       // 1048576
  float* sav = sak + 1048576;       // 1048576
  float* sao = sav + 1048576;       // 1048576 -> total 5,799,936 < 16,777,216

  // kp/vp survive into k_coord_pt (which overwrites d_out): keep in d_ws (512 KB).
  unsigned* kp=(unsigned*)d_ws;     // 65536 u32
  unsigned* vp=kp+65536;            // 65536 u32

  k_cb_kv<<<4096,128,0,stream>>>(cb,ca_cng,ca_cnb,ca_wkv,kcb,vcb);
  k_lat_q<<<512,64,0,stream>>>(latents,ca_ng,ca_nb,ca_wq,q1);
  k_attn1<<<dim3(512,4),256,0,stream>>>(q1,kcb,vcb,ca_wo,ca_bo,latents,x1);
  k_ffn<<<2048,256,0,stream>>>(x1,cf_ng,cf_nb,cf_w1,cf_b1,cf_w2,cf_b2,x2);
  k_sa_qkv<<<2048,256,0,stream>>>(x2,sa_ng,sa_nb,sa_wq,sa_wkv,saq,sak,sav);
  k_sa_attn<<<dim3(128,8,4),256,0,stream>>>(saq,sak,sav,sao);
  k_sa_proj<<<2048,256,0,stream>>>(sao,sa_wo,sa_bo,x2,x3);
  k_ffn<<<2048,256,0,stream>>>(x3,sf_ng,sf_nb,sf_w1,sf_b1,sf_w2,sf_b2,lat);
  k_kv2p<<<2048,128,0,stream>>>(lat,qa_cng,qa_cnb,qa_wkv,kp,vp);
  hipFuncSetAttribute((const void*)k_coord_pt,
                      hipFuncAttributeMaxDynamicSharedMemorySize, LDSU32*4);
  k_coord_pt<<<256,512,LDSU32*4,stream>>>(queries,kp,vp,qa_ng,qa_nb,qa_wq,qa_wo,qa_bo,out);
  k_ffq2<<<256,512,0,stream>>>(out,qf_ng,qf_nb,qf_w1,qf_b1,qf_w2,qf_b2);
}